// Round 3
// baseline (950.037 us; speedup 1.0000x reference)
//
#include <hip/hip_runtime.h>
#include <hip/hip_bf16.h>
#include <math.h>

#define N_TOK 4096
#define CDIM 1024
#define HDIM 2752
#define NEXP 8

typedef __bf16 bf16_t;
typedef __bf16 bf16x8 __attribute__((ext_vector_type(8)));
typedef float f32x4 __attribute__((ext_vector_type(4)));

__device__ __forceinline__ void gload_lds16(const void* g, void* l) {
  __builtin_amdgcn_global_load_lds(
      (const __attribute__((address_space(1))) unsigned int*)g,
      (__attribute__((address_space(3))) unsigned int*)l, 16, 0, 0);
}

// ---------------- generic f32 -> bf16 cast (elems % 1024 == 0) ----------------
__global__ void moe_cast(const float* __restrict__ in, bf16_t* __restrict__ outp) {
  size_t i = (size_t)blockIdx.x * 256 + threadIdx.x;  // one float4 per thread
  float4 v = ((const float4*)in)[i];
  union { bf16_t b[4]; unsigned long long u; } pk;
  pk.b[0] = (bf16_t)v.x; pk.b[1] = (bf16_t)v.y; pk.b[2] = (bf16_t)v.z; pk.b[3] = (bf16_t)v.w;
  ((unsigned long long*)outp)[i] = pk.u;
}

// ---------------- gating: logits (f64), top-2, softmax, fused x->bf16 cast ----------------
__global__ void moe_gating(const float* __restrict__ x, const float* __restrict__ gw,
                           int* __restrict__ top_i, float* __restrict__ top_w,
                           float* __restrict__ probs_tok, bf16_t* __restrict__ xb) {
  const int wid = threadIdx.x >> 6, lane = threadIdx.x & 63;
  const int n = blockIdx.x * 4 + wid;  // 1024 blocks x 4 waves
  const float* xr = x + (size_t)n * CDIM;
  float xv[16];
  for (int j = 0; j < 16; j += 4)
    *(float4*)&xv[j] = *(const float4*)(xr + lane * 16 + j);
  // fused cast: write bf16 row
  {
    union { bf16_t b[4]; unsigned long long u; } pk;
    unsigned long long* dst = (unsigned long long*)(xb + (size_t)n * CDIM + lane * 16);
    for (int j = 0; j < 16; j += 4) {
      pk.b[0] = (bf16_t)xv[j]; pk.b[1] = (bf16_t)xv[j+1];
      pk.b[2] = (bf16_t)xv[j+2]; pk.b[3] = (bf16_t)xv[j+3];
      dst[j >> 2] = pk.u;
    }
  }
  double part[NEXP];
  for (int e = 0; e < NEXP; ++e) {
    const float* gr = gw + e * CDIM + lane * 16;
    double s = 0.0;
    for (int j = 0; j < 16; j += 4) {
      float4 g = *(const float4*)(gr + j);
      s += (double)xv[j] * g.x + (double)xv[j+1] * g.y + (double)xv[j+2] * g.z + (double)xv[j+3] * g.w;
    }
    part[e] = s;
  }
  for (int off = 32; off; off >>= 1)
    for (int e = 0; e < NEXP; ++e) part[e] += __shfl_xor(part[e], off);
  if (lane == 0) {
    int i0 = 0; double l0 = part[0];
    for (int e = 1; e < NEXP; ++e) if (part[e] > l0) { l0 = part[e]; i0 = e; }
    int i1 = -1; double l1 = -1e300;
    for (int e = 0; e < NEXP; ++e) if (e != i0 && part[e] > l1) { l1 = part[e]; i1 = e; }
    double ed = exp(l1 - l0);                 // <= 1
    float w0 = (float)(1.0 / (1.0 + ed));
    float w1 = (float)(ed / (1.0 + ed));
    top_i[2*n] = i0; top_i[2*n+1] = i1;
    top_w[2*n] = w0; top_w[2*n+1] = w1;
    double Z = 0.0, pe[NEXP];
    for (int e = 0; e < NEXP; ++e) { pe[e] = exp(part[e] - l0); Z += pe[e]; }
    for (int e = 0; e < NEXP; ++e) probs_tok[(size_t)n * NEXP + e] = (float)(pe[e] / Z);
  }
}

// ---------------- deterministic reduce: counts + prob sums per expert ----------------
__global__ void moe_reduce(const float* __restrict__ probs_tok, const int* __restrict__ top_i,
                           int* __restrict__ cnts, float* __restrict__ probs_sum) {
  const int e = blockIdx.x, t = threadIdx.x;
  float s = 0.f; int c = 0;
  for (int n = t; n < N_TOK; n += 256) {
    s += probs_tok[(size_t)n * NEXP + e];
    c += (top_i[2*n] == e) + (top_i[2*n+1] == e);
  }
  __shared__ float ls[256]; __shared__ int lc[256];
  ls[t] = s; lc[t] = c; __syncthreads();
  for (int o = 128; o; o >>= 1) {
    if (t < o) { ls[t] += ls[t+o]; lc[t] += lc[t+o]; }
    __syncthreads();
  }
  if (t == 0) { cnts[e] = lc[0]; probs_sum[e] = ls[0]; }
}

// ---------------- prefix offsets + aux loss ----------------
__global__ void moe_prefix_aux(const int* __restrict__ cnts, int* __restrict__ offs,
                               int* __restrict__ cursors, const float* __restrict__ probs_sum,
                               float* __restrict__ out_aux) {
  if (threadIdx.x == 0) {
    int o = 0;
    for (int e = 0; e < NEXP; ++e) { offs[e] = o; o += cnts[e]; }
    double aux = 0.0;
    for (int e = 0; e < NEXP; ++e) aux += (double)cnts[e] * (double)probs_sum[e];
    out_aux[0] = (float)(0.01 * aux / ((double)N_TOK * (double)N_TOK));
  }
  if (threadIdx.x < NEXP) cursors[threadIdx.x] = 0;
}

// ---------------- scatter: wave-aggregated atomics ----------------
__global__ void moe_scatter(const int* __restrict__ top_i, const float* __restrict__ top_w,
                            const int* __restrict__ offs, int* __restrict__ cursors,
                            int* __restrict__ rowlist, float* __restrict__ wlist,
                            int* __restrict__ pair_pos) {
  const int wid = threadIdx.x >> 6, lane = threadIdx.x & 63;
  const int n = (blockIdx.x * 4 + wid) * 64 + lane;
  const unsigned long long lt = ((unsigned long long)1 << lane) - 1;
  const int e0 = top_i[2*n], e1 = top_i[2*n + 1];
  const float w0 = top_w[2*n], w1 = top_w[2*n + 1];
  for (int e = 0; e < NEXP; ++e) {
    unsigned long long m0 = __ballot(e0 == e);
    unsigned long long m1 = __ballot(e1 == e);
    int tot = __popcll(m0) + __popcll(m1);
    int base = 0;
    if (lane == 0 && tot) base = atomicAdd(&cursors[e], tot);
    base = __shfl(base, 0);
    if (e0 == e) {
      int p = offs[e] + base + __popcll(m0 & lt);
      rowlist[p] = n; wlist[p] = w0; pair_pos[2*n] = p;
    }
    if (e1 == e) {
      int p = offs[e] + base + __popcll(m0) + __popcll(m1 & lt);
      rowlist[p] = n; wlist[p] = w1; pair_pos[2*n + 1] = p;
    }
  }
}

// ---------------- fused gate+up GEMM, BM=256 BN=64(dual) BK=64, all-bf16 ----------------
// grid: x = m-block (fastest, weight-panel reuse), y = n-block, z = expert
template <bool ROUTED>
__launch_bounds__(256, 2)
__global__ void moe_gu(const bf16_t* __restrict__ xb,
                       const bf16_t* __restrict__ Wg_base, const bf16_t* __restrict__ Wu_base,
                       bf16_t* __restrict__ hout,
                       const int* __restrict__ rowlist, const int* __restrict__ offs,
                       const int* __restrict__ cnts) {
  const int e = blockIdx.z;
  int cnt, aoff;
  if (ROUTED) {
    cnt = cnts[e]; aoff = offs[e];
    if ((int)blockIdx.x * 256 >= cnt) return;
  } else { cnt = N_TOK; aoff = 0; }
  const bf16_t* Wg = Wg_base + (size_t)e * HDIM * CDIM;
  const bf16_t* Wu = Wu_base + (size_t)e * HDIM * CDIM;
  const int m0 = blockIdx.x * 256, n0 = blockIdx.y * 64;

  __shared__ alignas(16) bf16_t lA[256 * 64];   // 32 KB
  __shared__ alignas(16) bf16_t lBG[64 * 64];   // 8 KB
  __shared__ alignas(16) bf16_t lBU[64 * 64];   // 8 KB

  const int tid = threadIdx.x, wid = tid >> 6, lane = tid & 63;
  const int rsub = lane >> 3, seg = lane & 7;   // 8 lanes per 64-col row

  // hoist per-lane A tokens (8 staging instrs per wave)
  const bf16_t* gA[8];
  for (int i = 0; i < 8; ++i) {
    int r = wid * 64 + i * 8 + rsub;
    int tok;
    if (ROUTED) { int mm = m0 + r < cnt ? m0 + r : cnt - 1; tok = rowlist[aoff + mm]; }
    else tok = m0 + r;
    gA[i] = xb + (size_t)tok * CDIM + seg * 8;
  }
  const bf16_t* gBG = Wg + (size_t)(n0 + wid * 16 + rsub) * CDIM + seg * 8;
  const bf16_t* gBU = Wu + (size_t)(n0 + wid * 16 + rsub) * CDIM + seg * 8;

  f32x4 accG[4][4] = {}; f32x4 accU[4][4] = {};
  const int fr = lane & 15, hi = lane >> 4;

  for (int kt = 0; kt < CDIM / 64; ++kt) {
    if (kt) __syncthreads();
    for (int i = 0; i < 8; ++i)
      gload_lds16(gA[i] + kt * 64, lA + (wid * 64 + i * 8) * 64);
    gload_lds16(gBG + kt * 64, lBG + (wid * 16) * 64);
    gload_lds16(gBG + 8 * CDIM + kt * 64, lBG + (wid * 16 + 8) * 64);
    gload_lds16(gBU + kt * 64, lBU + (wid * 16) * 64);
    gload_lds16(gBU + 8 * CDIM + kt * 64, lBU + (wid * 16 + 8) * 64);
    __syncthreads();
    for (int kk = 0; kk < 2; ++kk) {
      const int kb = kk * 32 + hi * 8;
      bf16x8 a[4], bg[4], bu[4];
      for (int i = 0; i < 4; ++i) a[i]  = *(const bf16x8*)(lA  + (wid * 64 + i * 16 + fr) * 64 + kb);
      for (int j = 0; j < 4; ++j) { bg[j] = *(const bf16x8*)(lBG + (j * 16 + fr) * 64 + kb);
                                    bu[j] = *(const bf16x8*)(lBU + (j * 16 + fr) * 64 + kb); }
      for (int i = 0; i < 4; ++i)
        for (int j = 0; j < 4; ++j) {
          accG[i][j] = __builtin_amdgcn_mfma_f32_16x16x32_bf16(a[i], bg[j], accG[i][j], 0, 0, 0);
          accU[i][j] = __builtin_amdgcn_mfma_f32_16x16x32_bf16(a[i], bu[j], accU[i][j], 0, 0, 0);
        }
    }
  }
  // SwiGLU epilogue -> bf16 h
  for (int i = 0; i < 4; ++i)
    for (int j = 0; j < 4; ++j)
      for (int r = 0; r < 4; ++r) {
        int lm = wid * 64 + i * 16 + hi * 4 + r;
        if (ROUTED && m0 + lm >= cnt) continue;
        float g = accG[i][j][r], u = accU[i][j][r];
        float hv = (g / (1.f + __expf(-g))) * u;
        int col = n0 + j * 16 + fr;
        hout[(size_t)(aoff + m0 + lm) * HDIM + col] = (bf16_t)hv;
      }
}

// ---------------- down GEMM, BM=256 BN=64 BK=64, all-bf16 ----------------
template <bool ROUTED>
__launch_bounds__(256, 2)
__global__ void moe_down(const bf16_t* __restrict__ hin, const bf16_t* __restrict__ Wd_base,
                         float* __restrict__ outp, const float* __restrict__ wlist,
                         const int* __restrict__ offs, const int* __restrict__ cnts) {
  const int e = blockIdx.z;
  int cnt, aoff;
  if (ROUTED) {
    cnt = cnts[e]; aoff = offs[e];
    if ((int)blockIdx.x * 256 >= cnt) return;
  } else { cnt = N_TOK; aoff = 0; }
  const bf16_t* Wd = Wd_base + (size_t)e * CDIM * HDIM;
  const int m0 = blockIdx.x * 256, n0 = blockIdx.y * 64;

  __shared__ alignas(16) bf16_t lA[256 * 64];   // 32 KB
  __shared__ alignas(16) bf16_t lB[64 * 64];    // 8 KB

  const int tid = threadIdx.x, wid = tid >> 6, lane = tid & 63;
  const int rsub = lane >> 3, seg = lane & 7;

  const bf16_t* gA[8];
  for (int i = 0; i < 8; ++i) {
    int r = wid * 64 + i * 8 + rsub;
    int mm = (ROUTED && m0 + r >= cnt) ? cnt - 1 : m0 + r;
    gA[i] = hin + (size_t)(aoff + mm) * HDIM + seg * 8;
  }
  const bf16_t* gB = Wd + (size_t)(n0 + wid * 16 + rsub) * HDIM + seg * 8;

  f32x4 acc[4][4] = {};
  const int fr = lane & 15, hi = lane >> 4;

  for (int kt = 0; kt < HDIM / 64; ++kt) {
    if (kt) __syncthreads();
    for (int i = 0; i < 8; ++i)
      gload_lds16(gA[i] + kt * 64, lA + (wid * 64 + i * 8) * 64);
    gload_lds16(gB + kt * 64, lB + (wid * 16) * 64);
    gload_lds16(gB + 8 * HDIM + kt * 64, lB + (wid * 16 + 8) * 64);
    __syncthreads();
    for (int kk = 0; kk < 2; ++kk) {
      const int kb = kk * 32 + hi * 8;
      bf16x8 a[4], b[4];
      for (int i = 0; i < 4; ++i) a[i] = *(const bf16x8*)(lA + (wid * 64 + i * 16 + fr) * 64 + kb);
      for (int j = 0; j < 4; ++j) b[j] = *(const bf16x8*)(lB + (j * 16 + fr) * 64 + kb);
      for (int i = 0; i < 4; ++i)
        for (int j = 0; j < 4; ++j)
          acc[i][j] = __builtin_amdgcn_mfma_f32_16x16x32_bf16(a[i], b[j], acc[i][j], 0, 0, 0);
    }
  }
  for (int i = 0; i < 4; ++i)
    for (int j = 0; j < 4; ++j)
      for (int r = 0; r < 4; ++r) {
        int lm = wid * 64 + i * 16 + hi * 4 + r;
        if (ROUTED && m0 + lm >= cnt) continue;
        float v = acc[i][j][r];
        int col = n0 + j * 16 + fr;
        if (ROUTED) {
          int pos = aoff + m0 + lm;
          outp[(size_t)pos * CDIM + col] = v * wlist[pos];
        } else {
          outp[(size_t)(m0 + lm) * CDIM + col] = v;
        }
      }
}

// ---------------- combine: out = shared + w0*E0 + w1*E1 (weights pre-applied) ----------------
__global__ void moe_combine(float* __restrict__ outp, const float* __restrict__ eo,
                            const int* __restrict__ pair_pos) {
  size_t i4 = (size_t)blockIdx.x * 256 + threadIdx.x;  // float4 index
  int n = (int)(i4 >> 8);
  int c4 = (int)(i4 & 255);
  int p0 = pair_pos[2*n], p1 = pair_pos[2*n + 1];
  const float4* eo4 = (const float4*)eo;
  float4 a = ((const float4*)outp)[i4];
  float4 b = eo4[(size_t)p0 * 256 + c4];
  float4 c = eo4[(size_t)p1 * 256 + c4];
  float4 r;
  r.x = a.x + b.x + c.x; r.y = a.y + b.y + c.y;
  r.z = a.z + b.z + c.z; r.w = a.w + b.w + c.w;
  ((float4*)outp)[i4] = r;
}

extern "C" void kernel_launch(void* const* d_in, const int* in_sizes, int n_in,
                              void* d_out, int out_size, void* d_ws, size_t ws_size,
                              hipStream_t stream) {
  const float* x   = (const float*)d_in[0];
  const float* gw  = (const float*)d_in[1];
  const float* egw = (const float*)d_in[2];
  const float* euw = (const float*)d_in[3];
  const float* edw = (const float*)d_in[4];
  const float* sgw = (const float*)d_in[5];
  const float* suw = (const float*)d_in[6];
  const float* sdw = (const float*)d_in[7];
  float* out = (float*)d_out;

  char* ws = (char*)d_ws;
  size_t off = 0;
  auto alloc = [&](size_t bytes) -> void* {
    void* p = ws + off; off = (off + bytes + 255) & ~(size_t)255; return p;
  };
  const size_t EW = (size_t)NEXP * HDIM * CDIM;   // 22.5M elems
  const size_t SW = (size_t)HDIM * CDIM;          // 2.8M elems
  bf16_t* xb    = (bf16_t*)alloc((size_t)N_TOK * CDIM * 2);
  bf16_t* egw_b = (bf16_t*)alloc(EW * 2);
  bf16_t* euw_b = (bf16_t*)alloc(EW * 2);
  bf16_t* edw_b = (bf16_t*)alloc(EW * 2);
  bf16_t* sgw_b = (bf16_t*)alloc(SW * 2);
  bf16_t* suw_b = (bf16_t*)alloc(SW * 2);
  bf16_t* sdw_b = (bf16_t*)alloc(SW * 2);
  bf16_t* h     = (bf16_t*)alloc((size_t)(2 * N_TOK + 256) * HDIM * 2);
  float*  eo    = (float*)alloc((size_t)2 * N_TOK * CDIM * 4);
  int*    ctrl  = (int*)alloc(256);
  int* cnts = ctrl; int* cursors = ctrl + 8; int* offs = ctrl + 16;
  float* probs_sum = (float*)(ctrl + 24);
  int*   top_i    = (int*)alloc((size_t)N_TOK * 2 * 4);
  float* top_w    = (float*)alloc((size_t)N_TOK * 2 * 4);
  int*   pair_pos = (int*)alloc((size_t)N_TOK * 2 * 4);
  int*   rowlist  = (int*)alloc((size_t)2 * N_TOK * 4);
  float* wlist    = (float*)alloc((size_t)2 * N_TOK * 4);
  float* probs_tok = (float*)alloc((size_t)N_TOK * NEXP * 4);

  // weight precast f32 -> bf16
  moe_cast<<<(int)(EW / 1024), 256, 0, stream>>>(egw, egw_b);
  moe_cast<<<(int)(EW / 1024), 256, 0, stream>>>(euw, euw_b);
  moe_cast<<<(int)(EW / 1024), 256, 0, stream>>>(edw, edw_b);
  moe_cast<<<(int)(SW / 1024), 256, 0, stream>>>(sgw, sgw_b);
  moe_cast<<<(int)(SW / 1024), 256, 0, stream>>>(suw, suw_b);
  moe_cast<<<(int)(SW / 1024), 256, 0, stream>>>(sdw, sdw_b);

  moe_gating<<<1024, 256, 0, stream>>>(x, gw, top_i, top_w, probs_tok, xb);
  moe_reduce<<<NEXP, 256, 0, stream>>>(probs_tok, top_i, cnts, probs_sum);
  moe_prefix_aux<<<1, 64, 0, stream>>>(cnts, offs, cursors, probs_sum, out + (size_t)N_TOK * CDIM);
  moe_scatter<<<16, 256, 0, stream>>>(top_i, top_w, offs, cursors, rowlist, wlist, pair_pos);

  // shared expert (identity rows), h rows [0,4096)
  moe_gu<false><<<dim3(N_TOK / 256, HDIM / 64, 1), 256, 0, stream>>>(
      xb, sgw_b, suw_b, h, nullptr, nullptr, nullptr);
  moe_down<false><<<dim3(N_TOK / 256, CDIM / 64, 1), 256, 0, stream>>>(
      h, sdw_b, out, nullptr, nullptr, nullptr);
  // routed experts (gathered rows), h rows pos-indexed
  moe_gu<true><<<dim3(N_TOK / 256, HDIM / 64, NEXP), 256, 0, stream>>>(
      xb, egw_b, euw_b, h, rowlist, offs, cnts);
  moe_down<true><<<dim3(N_TOK / 256, CDIM / 64, NEXP), 256, 0, stream>>>(
      h, edw_b, eo, wlist, offs, cnts);
  moe_combine<<<4096, 256, 0, stream>>>(out, eo, pair_pos);
}

// Round 4
// 924.753 us; speedup vs baseline: 1.0273x; 1.0273x over previous
//
#include <hip/hip_runtime.h>
#include <hip/hip_bf16.h>
#include <math.h>

#define N_TOK 4096
#define CDIM 1024
#define HDIM 2752
#define NEXP 8

typedef __bf16 bf16_t;
typedef __bf16 bf16x8 __attribute__((ext_vector_type(8)));
typedef float f32x4 __attribute__((ext_vector_type(4)));

__device__ __forceinline__ void gload_lds16(const void* g, void* l) {
  __builtin_amdgcn_global_load_lds(
      (const __attribute__((address_space(1))) unsigned int*)g,
      (__attribute__((address_space(3))) unsigned int*)l, 16, 0, 0);
}

// ---------------- generic f32 -> bf16 cast (elems % 1024 == 0) ----------------
__global__ void moe_cast(const float* __restrict__ in, bf16_t* __restrict__ outp) {
  size_t i = (size_t)blockIdx.x * 256 + threadIdx.x;  // one float4 per thread
  float4 v = ((const float4*)in)[i];
  union { bf16_t b[4]; unsigned long long u; } pk;
  pk.b[0] = (bf16_t)v.x; pk.b[1] = (bf16_t)v.y; pk.b[2] = (bf16_t)v.z; pk.b[3] = (bf16_t)v.w;
  ((unsigned long long*)outp)[i] = pk.u;
}

// ---------------- gating: logits (f64), top-2, softmax, fused x->bf16 cast ----------------
__global__ void moe_gating(const float* __restrict__ x, const float* __restrict__ gw,
                           int* __restrict__ top_i, float* __restrict__ top_w,
                           float* __restrict__ probs_tok, bf16_t* __restrict__ xb) {
  const int wid = threadIdx.x >> 6, lane = threadIdx.x & 63;
  const int n = blockIdx.x * 4 + wid;  // 1024 blocks x 4 waves
  const float* xr = x + (size_t)n * CDIM;
  float xv[16];
  for (int j = 0; j < 16; j += 4)
    *(float4*)&xv[j] = *(const float4*)(xr + lane * 16 + j);
  // fused cast: write bf16 row
  {
    union { bf16_t b[4]; unsigned long long u; } pk;
    unsigned long long* dst = (unsigned long long*)(xb + (size_t)n * CDIM + lane * 16);
    for (int j = 0; j < 16; j += 4) {
      pk.b[0] = (bf16_t)xv[j]; pk.b[1] = (bf16_t)xv[j+1];
      pk.b[2] = (bf16_t)xv[j+2]; pk.b[3] = (bf16_t)xv[j+3];
      dst[j >> 2] = pk.u;
    }
  }
  double part[NEXP];
  for (int e = 0; e < NEXP; ++e) {
    const float* gr = gw + e * CDIM + lane * 16;
    double s = 0.0;
    for (int j = 0; j < 16; j += 4) {
      float4 g = *(const float4*)(gr + j);
      s += (double)xv[j] * g.x + (double)xv[j+1] * g.y + (double)xv[j+2] * g.z + (double)xv[j+3] * g.w;
    }
    part[e] = s;
  }
  for (int off = 32; off; off >>= 1)
    for (int e = 0; e < NEXP; ++e) part[e] += __shfl_xor(part[e], off);
  if (lane == 0) {
    int i0 = 0; double l0 = part[0];
    for (int e = 1; e < NEXP; ++e) if (part[e] > l0) { l0 = part[e]; i0 = e; }
    int i1 = -1; double l1 = -1e300;
    for (int e = 0; e < NEXP; ++e) if (e != i0 && part[e] > l1) { l1 = part[e]; i1 = e; }
    double ed = exp(l1 - l0);                 // <= 1
    float w0 = (float)(1.0 / (1.0 + ed));
    float w1 = (float)(ed / (1.0 + ed));
    top_i[2*n] = i0; top_i[2*n+1] = i1;
    top_w[2*n] = w0; top_w[2*n+1] = w1;
    double Z = 0.0, pe[NEXP];
    for (int e = 0; e < NEXP; ++e) { pe[e] = exp(part[e] - l0); Z += pe[e]; }
    for (int e = 0; e < NEXP; ++e) probs_tok[(size_t)n * NEXP + e] = (float)(pe[e] / Z);
  }
}

// ---------------- deterministic reduce: counts + prob sums per expert ----------------
__global__ void moe_reduce(const float* __restrict__ probs_tok, const int* __restrict__ top_i,
                           int* __restrict__ cnts, float* __restrict__ probs_sum) {
  const int e = blockIdx.x, t = threadIdx.x;
  float s = 0.f; int c = 0;
  for (int n = t; n < N_TOK; n += 256) {
    s += probs_tok[(size_t)n * NEXP + e];
    c += (top_i[2*n] == e) + (top_i[2*n+1] == e);
  }
  __shared__ float ls[256]; __shared__ int lc[256];
  ls[t] = s; lc[t] = c; __syncthreads();
  for (int o = 128; o; o >>= 1) {
    if (t < o) { ls[t] += ls[t+o]; lc[t] += lc[t+o]; }
    __syncthreads();
  }
  if (t == 0) { cnts[e] = lc[0]; probs_sum[e] = ls[0]; }
}

// ---------------- prefix offsets + aux loss ----------------
__global__ void moe_prefix_aux(const int* __restrict__ cnts, int* __restrict__ offs,
                               int* __restrict__ cursors, const float* __restrict__ probs_sum,
                               float* __restrict__ out_aux) {
  if (threadIdx.x == 0) {
    int o = 0;
    for (int e = 0; e < NEXP; ++e) { offs[e] = o; o += cnts[e]; }
    double aux = 0.0;
    for (int e = 0; e < NEXP; ++e) aux += (double)cnts[e] * (double)probs_sum[e];
    out_aux[0] = (float)(0.01 * aux / ((double)N_TOK * (double)N_TOK));
  }
  if (threadIdx.x < NEXP) cursors[threadIdx.x] = 0;
}

// ---------------- scatter: wave-aggregated atomics ----------------
__global__ void moe_scatter(const int* __restrict__ top_i, const float* __restrict__ top_w,
                            const int* __restrict__ offs, int* __restrict__ cursors,
                            int* __restrict__ rowlist, float* __restrict__ wlist,
                            int* __restrict__ pair_pos) {
  const int wid = threadIdx.x >> 6, lane = threadIdx.x & 63;
  const int n = (blockIdx.x * 4 + wid) * 64 + lane;
  const unsigned long long lt = ((unsigned long long)1 << lane) - 1;
  const int e0 = top_i[2*n], e1 = top_i[2*n + 1];
  const float w0 = top_w[2*n], w1 = top_w[2*n + 1];
  for (int e = 0; e < NEXP; ++e) {
    unsigned long long m0 = __ballot(e0 == e);
    unsigned long long m1 = __ballot(e1 == e);
    int tot = __popcll(m0) + __popcll(m1);
    int base = 0;
    if (lane == 0 && tot) base = atomicAdd(&cursors[e], tot);
    base = __shfl(base, 0);
    if (e0 == e) {
      int p = offs[e] + base + __popcll(m0 & lt);
      rowlist[p] = n; wlist[p] = w0; pair_pos[2*n] = p;
    }
    if (e1 == e) {
      int p = offs[e] + base + __popcll(m0) + __popcll(m1 & lt);
      rowlist[p] = n; wlist[p] = w1; pair_pos[2*n + 1] = p;
    }
  }
}

// ---------------- merged gate+up GEMM (routed z<8, shared z==8), BM=128 BN=64 BK=64 ----------------
// grid: x = m-block (fastest -> concurrent same-panel readers), y = n-block, z = expert/shared
__launch_bounds__(256)
__global__ void moe_gu(const bf16_t* __restrict__ xb,
                       const bf16_t* __restrict__ Wg_r, const bf16_t* __restrict__ Wu_r,
                       const bf16_t* __restrict__ Wg_s, const bf16_t* __restrict__ Wu_s,
                       bf16_t* __restrict__ hout,
                       const int* __restrict__ rowlist, const int* __restrict__ offs,
                       const int* __restrict__ cnts) {
  const int z = blockIdx.z;
  const bool routed = z < NEXP;
  int cnt, hbase, loff = 0;
  const bf16_t *Wg, *Wu;
  if (routed) {
    cnt = cnts[z]; loff = offs[z]; hbase = loff;
    if ((int)blockIdx.x * 128 >= cnt) return;
    Wg = Wg_r + (size_t)z * HDIM * CDIM;
    Wu = Wu_r + (size_t)z * HDIM * CDIM;
  } else {
    cnt = N_TOK; hbase = 2 * N_TOK;   // shared h rows live at [8192, 12288)
    Wg = Wg_s; Wu = Wu_s;
  }
  const int m0 = blockIdx.x * 128, n0 = blockIdx.y * 64;

  __shared__ alignas(16) bf16_t lA[128 * 64];   // 16 KB
  __shared__ alignas(16) bf16_t lBG[64 * 64];   // 8 KB
  __shared__ alignas(16) bf16_t lBU[64 * 64];   // 8 KB

  const int tid = threadIdx.x, wid = tid >> 6, lane = tid & 63;
  const int wm = wid >> 1, wn = wid & 1;
  const int rsub = lane >> 3, seg = lane & 7;   // 8 lanes cover one 64-col row

  const bf16_t* gA[4];
  for (int i = 0; i < 4; ++i) {
    int r = wid * 32 + i * 8 + rsub;
    int tok;
    if (routed) { int mm = m0 + r < cnt ? m0 + r : cnt - 1; tok = rowlist[loff + mm]; }
    else tok = m0 + r;
    gA[i] = xb + (size_t)tok * CDIM + seg * 8;
  }
  const bf16_t* gBG = Wg + (size_t)(n0 + wid * 16 + rsub) * CDIM + seg * 8;
  const bf16_t* gBU = Wu + (size_t)(n0 + wid * 16 + rsub) * CDIM + seg * 8;

  f32x4 accG[4][2] = {}; f32x4 accU[4][2] = {};
  const int fr = lane & 15, hi = lane >> 4;

  for (int kt = 0; kt < CDIM / 64; ++kt) {
    if (kt) __syncthreads();
    for (int i = 0; i < 4; ++i)
      gload_lds16(gA[i] + kt * 64, lA + (wid * 32 + i * 8) * 64);
    gload_lds16(gBG + kt * 64, lBG + (wid * 16) * 64);
    gload_lds16(gBG + 8 * CDIM + kt * 64, lBG + (wid * 16 + 8) * 64);
    gload_lds16(gBU + kt * 64, lBU + (wid * 16) * 64);
    gload_lds16(gBU + 8 * CDIM + kt * 64, lBU + (wid * 16 + 8) * 64);
    __syncthreads();
    for (int kk = 0; kk < 2; ++kk) {
      const int kb = kk * 32 + hi * 8;
      bf16x8 a[4], bg[2], bu[2];
      for (int i = 0; i < 4; ++i) a[i]  = *(const bf16x8*)(lA  + (wm * 64 + i * 16 + fr) * 64 + kb);
      for (int j = 0; j < 2; ++j) { bg[j] = *(const bf16x8*)(lBG + (wn * 32 + j * 16 + fr) * 64 + kb);
                                    bu[j] = *(const bf16x8*)(lBU + (wn * 32 + j * 16 + fr) * 64 + kb); }
      for (int i = 0; i < 4; ++i)
        for (int j = 0; j < 2; ++j) {
          accG[i][j] = __builtin_amdgcn_mfma_f32_16x16x32_bf16(a[i], bg[j], accG[i][j], 0, 0, 0);
          accU[i][j] = __builtin_amdgcn_mfma_f32_16x16x32_bf16(a[i], bu[j], accU[i][j], 0, 0, 0);
        }
    }
  }
  // SwiGLU epilogue -> bf16 h
  for (int i = 0; i < 4; ++i)
    for (int j = 0; j < 2; ++j)
      for (int r = 0; r < 4; ++r) {
        int lm = wm * 64 + i * 16 + hi * 4 + r;
        if (routed && m0 + lm >= cnt) continue;
        float g = accG[i][j][r], u = accU[i][j][r];
        float hv = (g / (1.f + __expf(-g))) * u;
        int col = n0 + wn * 32 + j * 16 + fr;
        hout[(size_t)(hbase + m0 + lm) * HDIM + col] = (bf16_t)hv;
      }
}

// ---------------- merged down GEMM (routed z<8 -> eo*w, shared z==8 -> out) ----------------
__launch_bounds__(256)
__global__ void moe_down(const bf16_t* __restrict__ hin, const bf16_t* __restrict__ Wd_r,
                         const bf16_t* __restrict__ Wd_s,
                         float* __restrict__ outp, float* __restrict__ eo,
                         const float* __restrict__ wlist,
                         const int* __restrict__ offs, const int* __restrict__ cnts) {
  const int z = blockIdx.z;
  const bool routed = z < NEXP;
  int cnt, hbase;
  const bf16_t* Wd;
  if (routed) {
    cnt = cnts[z]; hbase = offs[z];
    if ((int)blockIdx.x * 128 >= cnt) return;
    Wd = Wd_r + (size_t)z * CDIM * HDIM;
  } else {
    cnt = N_TOK; hbase = 2 * N_TOK;
    Wd = Wd_s;
  }
  const int m0 = blockIdx.x * 128, n0 = blockIdx.y * 64;

  __shared__ alignas(16) bf16_t lA[128 * 64];   // 16 KB
  __shared__ alignas(16) bf16_t lB[64 * 64];    // 8 KB

  const int tid = threadIdx.x, wid = tid >> 6, lane = tid & 63;
  const int wm = wid >> 1, wn = wid & 1;
  const int rsub = lane >> 3, seg = lane & 7;

  const bf16_t* gA[4];
  for (int i = 0; i < 4; ++i) {
    int r = wid * 32 + i * 8 + rsub;
    int mm = (routed && m0 + r >= cnt) ? cnt - 1 : m0 + r;
    gA[i] = hin + (size_t)(hbase + mm) * HDIM + seg * 8;
  }
  const bf16_t* gB = Wd + (size_t)(n0 + wid * 16 + rsub) * HDIM + seg * 8;

  f32x4 acc[4][2] = {};
  const int fr = lane & 15, hi = lane >> 4;

  for (int kt = 0; kt < HDIM / 64; ++kt) {
    if (kt) __syncthreads();
    for (int i = 0; i < 4; ++i)
      gload_lds16(gA[i] + kt * 64, lA + (wid * 32 + i * 8) * 64);
    gload_lds16(gB + kt * 64, lB + (wid * 16) * 64);
    gload_lds16(gB + 8 * HDIM + kt * 64, lB + (wid * 16 + 8) * 64);
    __syncthreads();
    for (int kk = 0; kk < 2; ++kk) {
      const int kb = kk * 32 + hi * 8;
      bf16x8 a[4], b[2];
      for (int i = 0; i < 4; ++i) a[i] = *(const bf16x8*)(lA + (wm * 64 + i * 16 + fr) * 64 + kb);
      for (int j = 0; j < 2; ++j) b[j] = *(const bf16x8*)(lB + (wn * 32 + j * 16 + fr) * 64 + kb);
      for (int i = 0; i < 4; ++i)
        for (int j = 0; j < 2; ++j)
          acc[i][j] = __builtin_amdgcn_mfma_f32_16x16x32_bf16(a[i], b[j], acc[i][j], 0, 0, 0);
    }
  }
  for (int i = 0; i < 4; ++i)
    for (int j = 0; j < 2; ++j)
      for (int r = 0; r < 4; ++r) {
        int lm = wm * 64 + i * 16 + hi * 4 + r;
        if (routed && m0 + lm >= cnt) continue;
        float v = acc[i][j][r];
        int col = n0 + wn * 32 + j * 16 + fr;
        if (routed) {
          int pos = hbase + m0 + lm;
          eo[(size_t)pos * CDIM + col] = v * wlist[pos];
        } else {
          outp[(size_t)(m0 + lm) * CDIM + col] = v;
        }
      }
}

// ---------------- combine: out = shared + w0*E0 + w1*E1 (weights pre-applied) ----------------
__global__ void moe_combine(float* __restrict__ outp, const float* __restrict__ eo,
                            const int* __restrict__ pair_pos) {
  size_t i4 = (size_t)blockIdx.x * 256 + threadIdx.x;  // float4 index
  int n = (int)(i4 >> 8);
  int c4 = (int)(i4 & 255);
  int p0 = pair_pos[2*n], p1 = pair_pos[2*n + 1];
  const float4* eo4 = (const float4*)eo;
  float4 a = ((const float4*)outp)[i4];
  float4 b = eo4[(size_t)p0 * 256 + c4];
  float4 c = eo4[(size_t)p1 * 256 + c4];
  float4 r;
  r.x = a.x + b.x + c.x; r.y = a.y + b.y + c.y;
  r.z = a.z + b.z + c.z; r.w = a.w + b.w + c.w;
  ((float4*)outp)[i4] = r;
}

extern "C" void kernel_launch(void* const* d_in, const int* in_sizes, int n_in,
                              void* d_out, int out_size, void* d_ws, size_t ws_size,
                              hipStream_t stream) {
  const float* x   = (const float*)d_in[0];
  const float* gw  = (const float*)d_in[1];
  const float* egw = (const float*)d_in[2];
  const float* euw = (const float*)d_in[3];
  const float* edw = (const float*)d_in[4];
  const float* sgw = (const float*)d_in[5];
  const float* suw = (const float*)d_in[6];
  const float* sdw = (const float*)d_in[7];
  float* out = (float*)d_out;

  char* ws = (char*)d_ws;
  size_t off = 0;
  auto alloc = [&](size_t bytes) -> void* {
    void* p = ws + off; off = (off + bytes + 255) & ~(size_t)255; return p;
  };
  const size_t EW = (size_t)NEXP * HDIM * CDIM;   // 22.5M elems
  const size_t SW = (size_t)HDIM * CDIM;          // 2.8M elems
  bf16_t* xb    = (bf16_t*)alloc((size_t)N_TOK * CDIM * 2);
  bf16_t* egw_b = (bf16_t*)alloc(EW * 2);
  bf16_t* euw_b = (bf16_t*)alloc(EW * 2);
  bf16_t* edw_b = (bf16_t*)alloc(EW * 2);
  bf16_t* sgw_b = (bf16_t*)alloc(SW * 2);
  bf16_t* suw_b = (bf16_t*)alloc(SW * 2);
  bf16_t* sdw_b = (bf16_t*)alloc(SW * 2);
  bf16_t* h     = (bf16_t*)alloc((size_t)(3 * N_TOK + 256) * HDIM * 2);  // routed [0,8192) + shared [8192,12288)
  float*  eo    = (float*)alloc((size_t)2 * N_TOK * CDIM * 4);
  int*    ctrl  = (int*)alloc(256);
  int* cnts = ctrl; int* cursors = ctrl + 8; int* offs = ctrl + 16;
  float* probs_sum = (float*)(ctrl + 24);
  int*   top_i    = (int*)alloc((size_t)N_TOK * 2 * 4);
  float* top_w    = (float*)alloc((size_t)N_TOK * 2 * 4);
  int*   pair_pos = (int*)alloc((size_t)N_TOK * 2 * 4);
  int*   rowlist  = (int*)alloc((size_t)2 * N_TOK * 4);
  float* wlist    = (float*)alloc((size_t)2 * N_TOK * 4);
  float* probs_tok = (float*)alloc((size_t)N_TOK * NEXP * 4);

  // weight precast f32 -> bf16
  moe_cast<<<(int)(EW / 1024), 256, 0, stream>>>(egw, egw_b);
  moe_cast<<<(int)(EW / 1024), 256, 0, stream>>>(euw, euw_b);
  moe_cast<<<(int)(EW / 1024), 256, 0, stream>>>(edw, edw_b);
  moe_cast<<<(int)(SW / 1024), 256, 0, stream>>>(sgw, sgw_b);
  moe_cast<<<(int)(SW / 1024), 256, 0, stream>>>(suw, suw_b);
  moe_cast<<<(int)(SW / 1024), 256, 0, stream>>>(sdw, sdw_b);

  moe_gating<<<1024, 256, 0, stream>>>(x, gw, top_i, top_w, probs_tok, xb);
  moe_reduce<<<NEXP, 256, 0, stream>>>(probs_tok, top_i, cnts, probs_sum);
  moe_prefix_aux<<<1, 64, 0, stream>>>(cnts, offs, cursors, probs_sum, out + (size_t)N_TOK * CDIM);
  moe_scatter<<<16, 256, 0, stream>>>(top_i, top_w, offs, cursors, rowlist, wlist, pair_pos);

  // merged gate+up: z 0..7 routed, z==8 shared
  moe_gu<<<dim3(N_TOK / 128, HDIM / 64, NEXP + 1), 256, 0, stream>>>(
      xb, egw_b, euw_b, sgw_b, suw_b, h, rowlist, offs, cnts);
  // merged down: z 0..7 routed -> eo (scaled), z==8 shared -> out
  moe_down<<<dim3(N_TOK / 128, CDIM / 64, NEXP + 1), 256, 0, stream>>>(
      h, edw_b, sdw_b, out, eo, wlist, offs, cnts);
  moe_combine<<<4096, 256, 0, stream>>>(out, eo, pair_pos);
}

// Round 5
// 499.160 us; speedup vs baseline: 1.9033x; 1.8526x over previous
//
#include <hip/hip_runtime.h>
#include <hip/hip_bf16.h>
#include <math.h>

#define N_TOK 4096
#define CDIM 1024
#define HDIM 2752
#define NEXP 8

typedef __bf16 bf16_t;
typedef __bf16 bf16x8 __attribute__((ext_vector_type(8)));
typedef float f32x4 __attribute__((ext_vector_type(4)));

__device__ __forceinline__ void gload_lds16(const void* g, void* l) {
  __builtin_amdgcn_global_load_lds(
      (const __attribute__((address_space(1))) unsigned int*)g,
      (__attribute__((address_space(3))) unsigned int*)l, 16, 0, 0);
}

// ---------------- generic f32 -> bf16 cast (elems % 1024 == 0) ----------------
__global__ void moe_cast(const float* __restrict__ in, bf16_t* __restrict__ outp) {
  size_t i = (size_t)blockIdx.x * 256 + threadIdx.x;  // one float4 per thread
  float4 v = ((const float4*)in)[i];
  union { bf16_t b[4]; unsigned long long u; } pk;
  pk.b[0] = (bf16_t)v.x; pk.b[1] = (bf16_t)v.y; pk.b[2] = (bf16_t)v.z; pk.b[3] = (bf16_t)v.w;
  ((unsigned long long*)outp)[i] = pk.u;
}

// ---------------- gating: logits (f64), top-2, softmax, fused x->bf16 cast ----------------
__global__ void moe_gating(const float* __restrict__ x, const float* __restrict__ gw,
                           int* __restrict__ top_i, float* __restrict__ top_w,
                           float* __restrict__ probs_tok, bf16_t* __restrict__ xb) {
  const int wid = threadIdx.x >> 6, lane = threadIdx.x & 63;
  const int n = blockIdx.x * 4 + wid;  // 1024 blocks x 4 waves
  const float* xr = x + (size_t)n * CDIM;
  float xv[16];
  for (int j = 0; j < 16; j += 4)
    *(float4*)&xv[j] = *(const float4*)(xr + lane * 16 + j);
  {
    union { bf16_t b[4]; unsigned long long u; } pk;
    unsigned long long* dst = (unsigned long long*)(xb + (size_t)n * CDIM + lane * 16);
    for (int j = 0; j < 16; j += 4) {
      pk.b[0] = (bf16_t)xv[j]; pk.b[1] = (bf16_t)xv[j+1];
      pk.b[2] = (bf16_t)xv[j+2]; pk.b[3] = (bf16_t)xv[j+3];
      dst[j >> 2] = pk.u;
    }
  }
  double part[NEXP];
  for (int e = 0; e < NEXP; ++e) {
    const float* gr = gw + e * CDIM + lane * 16;
    double s = 0.0;
    for (int j = 0; j < 16; j += 4) {
      float4 g = *(const float4*)(gr + j);
      s += (double)xv[j] * g.x + (double)xv[j+1] * g.y + (double)xv[j+2] * g.z + (double)xv[j+3] * g.w;
    }
    part[e] = s;
  }
  for (int off = 32; off; off >>= 1)
    for (int e = 0; e < NEXP; ++e) part[e] += __shfl_xor(part[e], off);
  if (lane == 0) {
    int i0 = 0; double l0 = part[0];
    for (int e = 1; e < NEXP; ++e) if (part[e] > l0) { l0 = part[e]; i0 = e; }
    int i1 = -1; double l1 = -1e300;
    for (int e = 0; e < NEXP; ++e) if (e != i0 && part[e] > l1) { l1 = part[e]; i1 = e; }
    double ed = exp(l1 - l0);                 // <= 1
    float w0 = (float)(1.0 / (1.0 + ed));
    float w1 = (float)(ed / (1.0 + ed));
    top_i[2*n] = i0; top_i[2*n+1] = i1;
    top_w[2*n] = w0; top_w[2*n+1] = w1;
    double Z = 0.0, pe[NEXP];
    for (int e = 0; e < NEXP; ++e) { pe[e] = exp(part[e] - l0); Z += pe[e]; }
    for (int e = 0; e < NEXP; ++e) probs_tok[(size_t)n * NEXP + e] = (float)(pe[e] / Z);
  }
}

// ---------------- deterministic reduce: counts + prob sums per expert ----------------
__global__ void moe_reduce(const float* __restrict__ probs_tok, const int* __restrict__ top_i,
                           int* __restrict__ cnts, float* __restrict__ probs_sum) {
  const int e = blockIdx.x, t = threadIdx.x;
  float s = 0.f; int c = 0;
  for (int n = t; n < N_TOK; n += 256) {
    s += probs_tok[(size_t)n * NEXP + e];
    c += (top_i[2*n] == e) + (top_i[2*n+1] == e);
  }
  __shared__ float ls[256]; __shared__ int lc[256];
  ls[t] = s; lc[t] = c; __syncthreads();
  for (int o = 128; o; o >>= 1) {
    if (t < o) { ls[t] += ls[t+o]; lc[t] += lc[t+o]; }
    __syncthreads();
  }
  if (t == 0) { cnts[e] = lc[0]; probs_sum[e] = ls[0]; }
}

// ---------------- prefix offsets + aux loss ----------------
__global__ void moe_prefix_aux(const int* __restrict__ cnts, int* __restrict__ offs,
                               int* __restrict__ cursors, const float* __restrict__ probs_sum,
                               float* __restrict__ out_aux) {
  if (threadIdx.x == 0) {
    int o = 0;
    for (int e = 0; e < NEXP; ++e) { offs[e] = o; o += cnts[e]; }
    double aux = 0.0;
    for (int e = 0; e < NEXP; ++e) aux += (double)cnts[e] * (double)probs_sum[e];
    out_aux[0] = (float)(0.01 * aux / ((double)N_TOK * (double)N_TOK));
  }
  if (threadIdx.x < NEXP) cursors[threadIdx.x] = 0;
}

// ---------------- scatter: wave-aggregated atomics ----------------
__global__ void moe_scatter(const int* __restrict__ top_i, const float* __restrict__ top_w,
                            const int* __restrict__ offs, int* __restrict__ cursors,
                            int* __restrict__ rowlist, float* __restrict__ wlist,
                            int* __restrict__ pair_pos) {
  const int wid = threadIdx.x >> 6, lane = threadIdx.x & 63;
  const int n = (blockIdx.x * 4 + wid) * 64 + lane;
  const unsigned long long lt = ((unsigned long long)1 << lane) - 1;
  const int e0 = top_i[2*n], e1 = top_i[2*n + 1];
  const float w0 = top_w[2*n], w1 = top_w[2*n + 1];
  for (int e = 0; e < NEXP; ++e) {
    unsigned long long m0 = __ballot(e0 == e);
    unsigned long long m1 = __ballot(e1 == e);
    int tot = __popcll(m0) + __popcll(m1);
    int base = 0;
    if (lane == 0 && tot) base = atomicAdd(&cursors[e], tot);
    base = __shfl(base, 0);
    if (e0 == e) {
      int p = offs[e] + base + __popcll(m0 & lt);
      rowlist[p] = n; wlist[p] = w0; pair_pos[2*n] = p;
    }
    if (e1 == e) {
      int p = offs[e] + base + __popcll(m0) + __popcll(m1 & lt);
      rowlist[p] = n; wlist[p] = w1; pair_pos[2*n + 1] = p;
    }
  }
}

// ---------------- gate+up GEMM, m97 density: BM=128, 64 h-cols, B = [Wg(64); Wu(64)] ----------------
// 4 waves; wave w owns m-rows [w*32, w*32+32), all 64 cols, both G and U.
// acc = accG[2][4] + accU[2][4] = 16 f32x4 (64 VGPR) -- m97-equivalent.
// grid: x = n-panel (fastest), y = m-block, z = expert (8) / shared (z==8)
__launch_bounds__(256)
__global__ void moe_gu(const bf16_t* __restrict__ xb,
                       const bf16_t* __restrict__ Wg_r, const bf16_t* __restrict__ Wu_r,
                       const bf16_t* __restrict__ Wg_s, const bf16_t* __restrict__ Wu_s,
                       bf16_t* __restrict__ hout,
                       const int* __restrict__ rowlist, const int* __restrict__ offs,
                       const int* __restrict__ cnts) {
  const int z = blockIdx.z;
  const bool routed = z < NEXP;
  int cnt, hbase, loff = 0;
  const bf16_t *Wg, *Wu;
  if (routed) {
    cnt = cnts[z]; loff = offs[z]; hbase = loff;
    if ((int)blockIdx.y * 128 >= cnt) return;
    Wg = Wg_r + (size_t)z * HDIM * CDIM;
    Wu = Wu_r + (size_t)z * HDIM * CDIM;
  } else {
    cnt = N_TOK; hbase = 2 * N_TOK;   // shared h rows at [8192, 12288)
    Wg = Wg_s; Wu = Wu_s;
  }
  const int m0 = blockIdx.y * 128, n0 = blockIdx.x * 64;

  __shared__ alignas(16) bf16_t lA[128 * 64];   // 16 KB
  __shared__ alignas(16) bf16_t lB[128 * 64];   // 16 KB: rows 0-63 = Wg, 64-127 = Wu

  const int tid = threadIdx.x, wid = tid >> 6, lane = tid & 63;
  const int r8 = lane >> 3, c8 = lane & 7;
  const int fr = lane & 15, hi = lane >> 4;

  const bf16_t* gA[4];
  for (int i = 0; i < 4; ++i) {
    int r = wid * 32 + i * 8 + r8;
    int tok;
    if (routed) { int mm = m0 + r < cnt ? m0 + r : cnt - 1; tok = rowlist[loff + mm]; }
    else tok = m0 + r;
    gA[i] = xb + (size_t)tok * CDIM + c8 * 8;
  }
  const bf16_t* gB[4];
  for (int i = 0; i < 4; ++i) {
    int br = wid * 32 + i * 8 + r8;
    gB[i] = (br < 64 ? Wg + (size_t)(n0 + br) * CDIM
                     : Wu + (size_t)(n0 + br - 64) * CDIM) + c8 * 8;
  }

  f32x4 accG[2][4] = {}; f32x4 accU[2][4] = {};

  for (int kt = 0; kt < CDIM / 64; ++kt) {
    if (kt) __syncthreads();
    for (int i = 0; i < 4; ++i) gload_lds16(gA[i] + kt * 64, lA + (wid * 32 + i * 8) * 64);
    for (int i = 0; i < 4; ++i) gload_lds16(gB[i] + kt * 64, lB + (wid * 32 + i * 8) * 64);
    __syncthreads();
    for (int kk = 0; kk < 2; ++kk) {
      const int kb = kk * 32 + hi * 8;
      bf16x8 a[2], bg[4], bu[4];
      for (int i = 0; i < 2; ++i) a[i] = *(const bf16x8*)(lA + (wid * 32 + i * 16 + fr) * 64 + kb);
      for (int j = 0; j < 4; ++j) {
        bg[j] = *(const bf16x8*)(lB + (j * 16 + fr) * 64 + kb);
        bu[j] = *(const bf16x8*)(lB + (64 + j * 16 + fr) * 64 + kb);
      }
      for (int i = 0; i < 2; ++i)
        for (int j = 0; j < 4; ++j) {
          accG[i][j] = __builtin_amdgcn_mfma_f32_16x16x32_bf16(a[i], bg[j], accG[i][j], 0, 0, 0);
          accU[i][j] = __builtin_amdgcn_mfma_f32_16x16x32_bf16(a[i], bu[j], accU[i][j], 0, 0, 0);
        }
    }
  }
  // SwiGLU epilogue -> bf16 h
  for (int i = 0; i < 2; ++i)
    for (int j = 0; j < 4; ++j)
      for (int r = 0; r < 4; ++r) {
        int lm = wid * 32 + i * 16 + hi * 4 + r;
        if (routed && m0 + lm >= cnt) continue;
        float g = accG[i][j][r], u = accU[i][j][r];
        float hv = (g / (1.f + __expf(-g))) * u;
        hout[(size_t)(hbase + m0 + lm) * HDIM + n0 + j * 16 + fr] = (bf16_t)hv;
      }
}

// ---------------- down GEMM, m97 exact: BM=128, BN=128, BK=64, 2x2 waves, acc[4][4] ----------------
__launch_bounds__(256)
__global__ void moe_down(const bf16_t* __restrict__ hin, const bf16_t* __restrict__ Wd_r,
                         const bf16_t* __restrict__ Wd_s,
                         float* __restrict__ outp, float* __restrict__ eo,
                         const float* __restrict__ wlist,
                         const int* __restrict__ offs, const int* __restrict__ cnts) {
  const int z = blockIdx.z;
  const bool routed = z < NEXP;
  int cnt, hbase;
  const bf16_t* Wd;
  if (routed) {
    cnt = cnts[z]; hbase = offs[z];
    if ((int)blockIdx.y * 128 >= cnt) return;
    Wd = Wd_r + (size_t)z * CDIM * HDIM;
  } else {
    cnt = N_TOK; hbase = 2 * N_TOK;
    Wd = Wd_s;
  }
  const int m0 = blockIdx.y * 128, n0 = blockIdx.x * 128;

  __shared__ alignas(16) bf16_t lA[128 * 64];   // 16 KB
  __shared__ alignas(16) bf16_t lB[128 * 64];   // 16 KB

  const int tid = threadIdx.x, wid = tid >> 6, lane = tid & 63;
  const int wm = wid >> 1, wn = wid & 1;
  const int r8 = lane >> 3, c8 = lane & 7;
  const int fr = lane & 15, hi = lane >> 4;

  const bf16_t* gA[4];
  for (int i = 0; i < 4; ++i) {
    int r = wid * 32 + i * 8 + r8;
    int mm = (routed && m0 + r >= cnt) ? cnt - 1 : m0 + r;
    gA[i] = hin + (size_t)(hbase + mm) * HDIM + c8 * 8;
  }
  const bf16_t* gB[4];
  for (int i = 0; i < 4; ++i) {
    int br = wid * 32 + i * 8 + r8;
    gB[i] = Wd + (size_t)(n0 + br) * HDIM + c8 * 8;
  }

  f32x4 acc[4][4] = {};

  for (int kt = 0; kt < HDIM / 64; ++kt) {
    if (kt) __syncthreads();
    for (int i = 0; i < 4; ++i) gload_lds16(gA[i] + kt * 64, lA + (wid * 32 + i * 8) * 64);
    for (int i = 0; i < 4; ++i) gload_lds16(gB[i] + kt * 64, lB + (wid * 32 + i * 8) * 64);
    __syncthreads();
    for (int kk = 0; kk < 2; ++kk) {
      const int kb = kk * 32 + hi * 8;
      bf16x8 a[4], b[4];
      for (int i = 0; i < 4; ++i) a[i] = *(const bf16x8*)(lA + (wm * 64 + i * 16 + fr) * 64 + kb);
      for (int j = 0; j < 4; ++j) b[j] = *(const bf16x8*)(lB + (wn * 64 + j * 16 + fr) * 64 + kb);
      for (int i = 0; i < 4; ++i)
        for (int j = 0; j < 4; ++j)
          acc[i][j] = __builtin_amdgcn_mfma_f32_16x16x32_bf16(a[i], b[j], acc[i][j], 0, 0, 0);
    }
  }
  for (int i = 0; i < 4; ++i)
    for (int j = 0; j < 4; ++j)
      for (int r = 0; r < 4; ++r) {
        int lm = wm * 64 + i * 16 + hi * 4 + r;
        if (routed && m0 + lm >= cnt) continue;
        float v = acc[i][j][r];
        int col = n0 + wn * 64 + j * 16 + fr;
        if (routed) {
          int pos = hbase + m0 + lm;
          eo[(size_t)pos * CDIM + col] = v * wlist[pos];
        } else {
          outp[(size_t)(m0 + lm) * CDIM + col] = v;
        }
      }
}

// ---------------- combine: out = shared + w0*E0 + w1*E1 (weights pre-applied) ----------------
__global__ void moe_combine(float* __restrict__ outp, const float* __restrict__ eo,
                            const int* __restrict__ pair_pos) {
  size_t i4 = (size_t)blockIdx.x * 256 + threadIdx.x;  // float4 index
  int n = (int)(i4 >> 8);
  int c4 = (int)(i4 & 255);
  int p0 = pair_pos[2*n], p1 = pair_pos[2*n + 1];
  const float4* eo4 = (const float4*)eo;
  float4 a = ((const float4*)outp)[i4];
  float4 b = eo4[(size_t)p0 * 256 + c4];
  float4 c = eo4[(size_t)p1 * 256 + c4];
  float4 r;
  r.x = a.x + b.x + c.x; r.y = a.y + b.y + c.y;
  r.z = a.z + b.z + c.z; r.w = a.w + b.w + c.w;
  ((float4*)outp)[i4] = r;
}

extern "C" void kernel_launch(void* const* d_in, const int* in_sizes, int n_in,
                              void* d_out, int out_size, void* d_ws, size_t ws_size,
                              hipStream_t stream) {
  const float* x   = (const float*)d_in[0];
  const float* gw  = (const float*)d_in[1];
  const float* egw = (const float*)d_in[2];
  const float* euw = (const float*)d_in[3];
  const float* edw = (const float*)d_in[4];
  const float* sgw = (const float*)d_in[5];
  const float* suw = (const float*)d_in[6];
  const float* sdw = (const float*)d_in[7];
  float* out = (float*)d_out;

  char* ws = (char*)d_ws;
  size_t off = 0;
  auto alloc = [&](size_t bytes) -> void* {
    void* p = ws + off; off = (off + bytes + 255) & ~(size_t)255; return p;
  };
  const size_t EW = (size_t)NEXP * HDIM * CDIM;   // 22.5M elems
  const size_t SW = (size_t)HDIM * CDIM;          // 2.8M elems
  bf16_t* xb    = (bf16_t*)alloc((size_t)N_TOK * CDIM * 2);
  bf16_t* egw_b = (bf16_t*)alloc(EW * 2);
  bf16_t* euw_b = (bf16_t*)alloc(EW * 2);
  bf16_t* edw_b = (bf16_t*)alloc(EW * 2);
  bf16_t* sgw_b = (bf16_t*)alloc(SW * 2);
  bf16_t* suw_b = (bf16_t*)alloc(SW * 2);
  bf16_t* sdw_b = (bf16_t*)alloc(SW * 2);
  bf16_t* h     = (bf16_t*)alloc((size_t)(3 * N_TOK + 256) * HDIM * 2);  // routed [0,8192) + shared [8192,12288)
  float*  eo    = (float*)alloc((size_t)2 * N_TOK * CDIM * 4);
  int*    ctrl  = (int*)alloc(256);
  int* cnts = ctrl; int* cursors = ctrl + 8; int* offs = ctrl + 16;
  float* probs_sum = (float*)(ctrl + 24);
  int*   top_i    = (int*)alloc((size_t)N_TOK * 2 * 4);
  float* top_w    = (float*)alloc((size_t)N_TOK * 2 * 4);
  int*   pair_pos = (int*)alloc((size_t)N_TOK * 2 * 4);
  int*   rowlist  = (int*)alloc((size_t)2 * N_TOK * 4);
  float* wlist    = (float*)alloc((size_t)2 * N_TOK * 4);
  float* probs_tok = (float*)alloc((size_t)N_TOK * NEXP * 4);

  // weight precast f32 -> bf16
  moe_cast<<<(int)(EW / 1024), 256, 0, stream>>>(egw, egw_b);
  moe_cast<<<(int)(EW / 1024), 256, 0, stream>>>(euw, euw_b);
  moe_cast<<<(int)(EW / 1024), 256, 0, stream>>>(edw, edw_b);
  moe_cast<<<(int)(SW / 1024), 256, 0, stream>>>(sgw, sgw_b);
  moe_cast<<<(int)(SW / 1024), 256, 0, stream>>>(suw, suw_b);
  moe_cast<<<(int)(SW / 1024), 256, 0, stream>>>(sdw, sdw_b);

  moe_gating<<<1024, 256, 0, stream>>>(x, gw, top_i, top_w, probs_tok, xb);
  moe_reduce<<<NEXP, 256, 0, stream>>>(probs_tok, top_i, cnts, probs_sum);
  moe_prefix_aux<<<1, 64, 0, stream>>>(cnts, offs, cursors, probs_sum, out + (size_t)N_TOK * CDIM);
  moe_scatter<<<16, 256, 0, stream>>>(top_i, top_w, offs, cursors, rowlist, wlist, pair_pos);

  // gate+up: x = n-panel (43), y = m-block (32), z = 8 routed + 1 shared
  moe_gu<<<dim3(HDIM / 64, N_TOK / 128, NEXP + 1), 256, 0, stream>>>(
      xb, egw_b, euw_b, sgw_b, suw_b, h, rowlist, offs, cnts);
  // down: x = n-panel (8, BN=128), y = m-block, z = 8 routed + 1 shared
  moe_down<<<dim3(CDIM / 128, N_TOK / 128, NEXP + 1), 256, 0, stream>>>(
      h, edw_b, sdw_b, out, eo, wlist, offs, cnts);
  moe_combine<<<4096, 256, 0, stream>>>(out, eo, pair_pos);
}